// Round 12
// baseline (3353.954 us; speedup 1.0000x reference)
//
#include <hip/hip_runtime.h>

// ---------- types ----------
typedef _Float16 h8 __attribute__((ext_vector_type(8)));
typedef _Float16 h4 __attribute__((ext_vector_type(4)));
typedef float    f4 __attribute__((ext_vector_type(4)));
typedef unsigned long long u64;

#define NBLK 256   // persistent grid = 256 blocks = 1 per CU

__device__ __forceinline__ float sigm(float x) {
    return 1.0f / (1.0f + __expf(-x));
}
__device__ __forceinline__ float tanh_fast(float x) {
    return 1.0f - 2.0f / (__expf(2.0f * x) + 1.0f);   // saturates correctly at +/-inf
}

// FLAT fence-free barrier (per-mg, 128 blocks).
// R11 post-mortem: go-flag tree (grp RMW -> root RMW -> 128-flag broadcast)
// was NEUTRAL vs flat-poll -> same-line LLC polling is CHEAP; the cost is the
// SERIAL chain of dependent LLC hops. So: collapse to the minimum —
//   arrive: one sc1 store of (t+1) to the block's OWN slot (no RMW, no tree);
//   wait:   wave-parallel sweep — 64 lanes of wave 0 each poll 2 of the mg's
//           128 slots, __all() ballot -> one load-latency per sweep.
// Slots are monotonic (store t+1), so relaxed agent-scope ops suffice; a
// sweep can only see a slot value that is current-or-older -> never exits
// early. h-store visibility: producer's __syncthreads drains vmcnt(0) (sc1
// h-stores LLC-acked) BEFORE its slot store issues -> slot==t+1 implies that
// block's h(t+1) is LLC-visible.
__device__ __forceinline__ void bar_arrive(unsigned* slot, int bid, unsigned barno) {
    __syncthreads();   // s_waitcnt vmcnt(0): all sc1 h-stores acked at LLC
    if (threadIdx.x == 0)
        __hip_atomic_store(&slot[bid * 64], barno + 1u, __ATOMIC_RELAXED,
                           __HIP_MEMORY_SCOPE_AGENT);
    // NO trailing sync: other waves fall through into h-independent work.
}
__device__ __forceinline__ void bar_wait(unsigned* slot, int mg, unsigned barno) {
    if (threadIdx.x < 64) {
        const unsigned tgt = barno + 1u;
        unsigned* p0 = &slot[(mg * 128 + threadIdx.x) * 64];
        unsigned* p1 = p0 + 64 * 64;
        unsigned spins = 0;
        for (;;) {
            unsigned v0 = __hip_atomic_load(p0, __ATOMIC_RELAXED,
                                            __HIP_MEMORY_SCOPE_AGENT);
            unsigned v1 = __hip_atomic_load(p1, __ATOMIC_RELAXED,
                                            __HIP_MEMORY_SCOPE_AGENT);
            if (__all(v0 >= tgt && v1 >= tgt)) break;
            __builtin_amdgcn_s_sleep(2);
            if (++spins > (1u << 24)) break;   // safety valve: corrupt-but-return
        }
    }
    __syncthreads();   // drains the overlapped out-stores + x loads (L2-fast now)
}

// ---------- prep: zero slots + h buffer 0, fp32 x -> fp16 ----------
__global__ void prep_kernel(const float* __restrict__ x, _Float16* __restrict__ xbuf,
                            unsigned* __restrict__ ctr, unsigned* __restrict__ hb0u) {
    const int gtid = blockIdx.x * blockDim.x + threadIdx.x;
    if (gtid < 16384) ctr[gtid] = 0u;         // 256 slots x 256-B stride = 64 KB
    if (gtid < 65536) hb0u[gtid] = 0u;        // h(0): 128x1024 fp16 = 256 KB
    const f4* src = (const f4*)x;
    h4* dst = (h4*)xbuf;
    const int stride = gridDim.x * blockDim.x;    // 524288
    for (int i = gtid; i < 8388608; i += stride)  // T*B*D/4
        dst[i] = __builtin_convertvector(src[i], h4);
}

// ---------- persistent LSTM ----------
// 256 blocks x 256 threads. Block b: mg = b>>7 (rows mg*64..+63), ug = b&127,
// units u0 = ug*8 .. +7, all 4 gates -> 32 preact cols (2 MFMA n-tiles).
// ALL of W (K=2048) in LDS, conflict-free chunk layout (see staging below).
// Loop structure per step t:
//   [a-regs already hold the x-half partial sums for step t]
//   bar_wait(t-1)            <- all 128 mg slots reached t (wave-parallel sweep)
//   h-half MFMAs (kc 32..63) <- ROT: plain cached h8 loads (fresh addresses)
//   epilogue: activations, c/h update, h(t+1) via packed sc1 atomic stores
//   bar_arrive(t)            <- vmcnt(0) drain, own-slot store (1 LLC hop)
//   out stores for step t    <- NORMAL cached stores (L2-ack; nt removed: no
//                               wbl2 exists since R7, nt only added HBM-ack
//                               drain at the next __syncthreads)
//   x-half MFMAs for t+1     <- executes INSIDE the barrier window
#define XHALF                                                                  \
    _Pragma("unroll")                                                          \
    for (int kc = 0; kc < 32; kc += 2) {                                       \
        h8 av0 = *(const h8*)(xA + kc * 32);                                   \
        h8 av1 = *(const h8*)(xA + kc * 32 + 32);                              \
        h8 b00 = *(const h8*)&wsm[kc * 1024 + boff];                           \
        h8 b10 = *(const h8*)&wsm[kc * 1024 + boff + 512];                     \
        h8 b01 = *(const h8*)&wsm[(kc + 1) * 1024 + boff];                     \
        h8 b11 = *(const h8*)&wsm[(kc + 1) * 1024 + boff + 512];               \
        a00 = __builtin_amdgcn_mfma_f32_16x16x32_f16(av0, b00, a00, 0, 0, 0);  \
        a10 = __builtin_amdgcn_mfma_f32_16x16x32_f16(av0, b10, a10, 0, 0, 0);  \
        a01 = __builtin_amdgcn_mfma_f32_16x16x32_f16(av1, b01, a01, 0, 0, 0);  \
        a11 = __builtin_amdgcn_mfma_f32_16x16x32_f16(av1, b11, a11, 0, 0, 0);  \
    }

// sc1 (LLC-coherent) h8 load: two agent-relaxed u64 atomic loads (PP fallback).
#define LDH8(dst, elemoff)                                                     \
    do {                                                                       \
        union { u64 q[2]; h8 v; } u_;                                          \
        u64* p_ = (u64*)(hA + (elemoff));                                      \
        u_.q[0] = __hip_atomic_load(p_,     __ATOMIC_RELAXED,                  \
                                    __HIP_MEMORY_SCOPE_AGENT);                 \
        u_.q[1] = __hip_atomic_load(p_ + 1, __ATOMIC_RELAXED,                  \
                                    __HIP_MEMORY_SCOPE_AGENT);                 \
        dst = u_.v;                                                            \
    } while (0)

template<bool ROT>
__global__ __launch_bounds__(256, 1)
void lstm_kernel(const _Float16* __restrict__ xbuf,
                 _Float16* __restrict__ hb0, _Float16* __restrict__ hb1,
                 const float* __restrict__ Wf, const float* __restrict__ bfp,
                 const float* __restrict__ Wi, const float* __restrict__ bip,
                 const float* __restrict__ Wg, const float* __restrict__ bgp,
                 const float* __restrict__ Wo, const float* __restrict__ bop,
                 float* __restrict__ out,
                 unsigned* __restrict__ slot) {
    __shared__ _Float16 wsm[64 * 1024];   // 128 KB: full W slice, chunked

    const int tid = threadIdx.x;
    const int bid = blockIdx.x;
    const int mg = bid >> 7;
    const int ug = bid & 127;
    const int u0 = ug << 3;

    const float* WSEL[4] = {Wf, Wi, Wg, Wo};

    // ---- stage W slice (32 cols x 2048 k) fp32 -> fp16 LDS, chunked ----
    // f16 idx = kc*1024 + tile*512 + quad*128 + row16*8 + j
    // (kc = k>>5, quad = (k>>3)&3, j = k&7, col = tile*16 + row16)
    // Read addr for lane L (= quad*16+row16): byte = kc*2048 + tile*1024 + L*16
    //   -> perfectly contiguous 16 B/lane -> zero bank conflicts.
    {
        const int col = tid & 31;                  // preact col
        const int kseg = tid >> 5;                 // 0..7, 256 k each
        const float* srcp = WSEL[col >> 3] + (size_t)(u0 + (col & 7)) * 2048
                          + kseg * 256;
        const int cbase = (col >> 4) * 512 + (col & 15) * 8;
#pragma unroll 8
        for (int k4 = 0; k4 < 256; k4 += 4) {
            const int k = kseg * 256 + k4;
            f4 v = *(const f4*)(srcp + k4);
            h4 hv = __builtin_convertvector(v, h4);
            *(h4*)&wsm[(k >> 5) * 1024 + cbase + ((k >> 3) & 3) * 128 + (k & 7)] = hv;
        }
    }

    // ---- per-lane constants ----
    const int lane  = tid & 63;
    const int wv    = tid >> 6;        // wave -> m-strip
    const int row16 = lane & 15;
    const int quad  = lane >> 4;
    const int uu    = lane & 7;

    __syncthreads();   // W staged (block-local)

    const float bias_f = bfp[u0 + uu];
    const float bias_i = bip[u0 + uu];
    const float bias_g = bgp[u0 + uu];
    const float bias_o = bop[u0 + uu];

    const int zrow = mg * 64 + wv * 16 + row16;
    const int boff = quad * 128 + row16 * 8;      // lane*8 f16 = lane*16 B
    const int drow = mg * 64 + wv * 16 + quad * 4;
    const bool writer = (lane & 8) == 0;
    const bool pstore = writer && ((uu & 1) == 0);   // even-unit writer: packs pair
    const bool himask = (lane & 8) != 0;

    const _Float16* hbv[2] = {hb0, hb1};
    const size_t aoff = (size_t)zrow * 1024 + quad * 8;
    const _Float16* xbase = xbuf + aoff;
    const size_t obase = (size_t)drow * 1024 + u0 + uu;   // row j adds j*1024

    float cc[4] = {0.f, 0.f, 0.f, 0.f};
    float hnv[4];                                  // step-t h values, stored late

    // ---- prologue: x-half for t = 0 (h(0)=0 already staged by prep) ----
    f4 a00 = {0.f,0.f,0.f,0.f}, a01 = {0.f,0.f,0.f,0.f};
    f4 a10 = {0.f,0.f,0.f,0.f}, a11 = {0.f,0.f,0.f,0.f};
    {
        const _Float16* xA = xbase;
        XHALF
    }

    for (int t = 0; t < 256; ++t) {
        if (t) bar_wait(slot, mg, (unsigned)(t - 1));   // h(t) released

        const _Float16* hA = (ROT ? hb0 + (size_t)t * 131072 : hbv[t & 1]) + aoff;
        unsigned* hwu = (unsigned*)(ROT ? hb0 + (size_t)(t + 1) * 131072
                                        : hbv[(t + 1) & 1]);

        // h half: k chunks 32..63 (the only h-dependent work)
#pragma unroll
        for (int kc = 32; kc < 64; kc += 2) {
            h8 av0, av1;
            if constexpr (ROT) {
                // plain cached loads: address is write-once/read-once, so no
                // stale L1/L2 line can exist; miss path reads fresh LLC data
                av0 = *(const h8*)(hA + (kc - 32) * 32);
                av1 = *(const h8*)(hA + (kc - 32) * 32 + 32);
            } else {
                LDH8(av0, (kc - 32) * 32);
                LDH8(av1, (kc - 32) * 32 + 32);
            }
            h8 b00 = *(const h8*)&wsm[kc * 1024 + boff];
            h8 b10 = *(const h8*)&wsm[kc * 1024 + boff + 512];
            h8 b01 = *(const h8*)&wsm[(kc + 1) * 1024 + boff];
            h8 b11 = *(const h8*)&wsm[(kc + 1) * 1024 + boff + 512];
            a00 = __builtin_amdgcn_mfma_f32_16x16x32_f16(av0, b00, a00, 0, 0, 0);
            a10 = __builtin_amdgcn_mfma_f32_16x16x32_f16(av0, b10, a10, 0, 0, 0);
            a01 = __builtin_amdgcn_mfma_f32_16x16x32_f16(av1, b01, a01, 0, 0, 0);
            a11 = __builtin_amdgcn_mfma_f32_16x16x32_f16(av1, b11, a11, 0, 0, 0);
        }

        // ---- epilogue: gather gate pairs, activations, state update ----
        f4 s0 = a00 + a01;   // tile0: f|i preacts, col = lane&15
        f4 s1 = a10 + a11;   // tile1: g|o preacts
        float q0[4], q1[4];
#pragma unroll
        for (int j = 0; j < 4; ++j) {
            q0[j] = __shfl_xor(s0[j], 8, 64);
            q1[j] = __shfl_xor(s1[j], 8, 64);
        }
#pragma unroll
        for (int j = 0; j < 4; ++j) {
            float pf = himask ? q0[j] : s0[j];
            float pi = himask ? s0[j] : q0[j];
            float pg = himask ? q1[j] : s1[j];
            float po = himask ? s1[j] : q1[j];
            float fg = sigm(pf + bias_f);
            float ig = sigm(pi + bias_i);
            float gg = tanh_fast(pg + bias_g);
            float og = sigm(po + bias_o);
            float cn = fg * cc[j] + ig * gg;
            cc[j] = cn;
            float hn = og * tanh_fast(cn);
            hnv[j] = hn;
            // h(t+1) feedback: packed 2xfp16 agent-atomic store (sc1 ->
            // write-through to LLC; no dirty L2 line, no fence needed).
            float hp = __shfl_xor(hn, 1, 64);     // odd neighbor's value
            if (pstore) {
                _Float16 alo = (_Float16)hn, ahi = (_Float16)hp;
                unsigned short blo, bhi;
                __builtin_memcpy(&blo, &alo, 2);
                __builtin_memcpy(&bhi, &ahi, 2);
                unsigned pk = (unsigned)blo | ((unsigned)bhi << 16);
                __hip_atomic_store(&hwu[(obase >> 1) + (size_t)j * 512], pk,
                                   __ATOMIC_RELAXED, __HIP_MEMORY_SCOPE_AGENT);
            }
        }

        if (t < 255) {
            bar_arrive(slot, bid, (unsigned)t);  // vmcnt(0) drain + own-slot store
            // out stores for step t: NORMAL cached (L2-ack ~fast). They drain
            // at the NEXT bar_wait's __syncthreads, overlapped w/ sweep+XHALF.
            if (writer) {
                float* outb = out + (size_t)t * 131072;
#pragma unroll
                for (int j = 0; j < 4; ++j)
                    outb[obase + (size_t)j * 1024] = hnv[j];
            }
            // x-half for t+1: h-independent, runs inside the barrier window
            a00 = (f4){0.f,0.f,0.f,0.f}; a01 = (f4){0.f,0.f,0.f,0.f};
            a10 = (f4){0.f,0.f,0.f,0.f}; a11 = (f4){0.f,0.f,0.f,0.f};
            const _Float16* xA = xbase + (size_t)(t + 1) * 131072;
            XHALF
        } else if (writer) {
            // t = 255: no barrier follows; store outputs[255] + hx directly
            float* outb = out + (size_t)255 * 131072;
#pragma unroll
            for (int j = 0; j < 4; ++j) {
                outb[obase + (size_t)j * 1024] = hnv[j];
                out[33554432 + obase + (size_t)j * 1024] = hnv[j];
            }
        }
    }
    // cx
    if (writer) {
#pragma unroll
        for (int j = 0; j < 4; ++j)
            out[33554432 + 131072 + obase + (size_t)j * 1024] = cc[j];
    }
}

extern "C" void kernel_launch(void* const* d_in, const int* in_sizes, int n_in,
                              void* d_out, int out_size, void* d_ws, size_t ws_size,
                              hipStream_t stream) {
    const float* x  = (const float*)d_in[0];
    const float* Wf = (const float*)d_in[1];
    const float* bf = (const float*)d_in[2];
    const float* Wi = (const float*)d_in[3];
    const float* bi = (const float*)d_in[4];
    const float* Wg = (const float*)d_in[5];
    const float* bg = (const float*)d_in[6];
    const float* Wo = (const float*)d_in[7];
    const float* bo = (const float*)d_in[8];
    float* out = (float*)d_out;

    unsigned char* ws = (unsigned char*)d_ws;
    unsigned* slot = (unsigned*)ws;                       // 256 slots, 256-B stride
    _Float16* hbase = (_Float16*)(ws + 65536);            // rot: 257 bufs / pp: hb0

    // Rotating layout: slots 64 KB | h buffers 257 x 256 KB | xbuf 64 MB
    const size_t HROT = 257ull * 262144ull;               // 67,371,008 B
    const size_t ROT_NEED = 65536ull + HROT + 67108864ull;
    const bool rot = (ws_size >= ROT_NEED);

    _Float16* hb1  = (_Float16*)(ws + 65536 + 262144);    // pp fallback only
    _Float16* xbuf = rot ? (_Float16*)(ws + 65536 + HROT)
                         : (_Float16*)(ws + 65536 + 524288);

    prep_kernel<<<2048, 256, 0, stream>>>(x, xbuf, slot, (unsigned*)hbase);
    if (rot)
        lstm_kernel<true><<<NBLK, 256, 0, stream>>>(xbuf, hbase, hb1,
                                                    Wf, bf, Wi, bi, Wg, bg, Wo, bo,
                                                    out, slot);
    else
        lstm_kernel<false><<<NBLK, 256, 0, stream>>>(xbuf, hbase, hb1,
                                                     Wf, bf, Wi, bi, Wg, bg, Wo, bo,
                                                     out, slot);
}

// Round 18
// 3219.035 us; speedup vs baseline: 1.0419x; 1.0419x over previous
//
#include <hip/hip_runtime.h>

// ---------- types ----------
typedef _Float16 h8 __attribute__((ext_vector_type(8)));
typedef _Float16 h4 __attribute__((ext_vector_type(4)));
typedef float    f4 __attribute__((ext_vector_type(4)));
typedef unsigned long long u64;

#define NBLK 256   // persistent grid = 256 blocks = 1 per CU

__device__ __forceinline__ float sigm(float x) {
    return 1.0f / (1.0f + __expf(-x));
}
__device__ __forceinline__ float tanh_fast(float x) {
    return 1.0f - 2.0f / (__expf(2.0f * x) + 1.0f);   // saturates correctly at +/-inf
}

// FLAT fence-free barrier (per-mg, 128 blocks), BUSY-POLL edition.
// R11/R12 negatives: barrier topology (tree vs flat) and poll-line sharing are
// both perf-neutral -> the ~12us/step floor is NOT notification structure.
// Work terms at full clock sum to ~3.4us/step; the uniform ~3.7x gap points at
// CLOCK THROTTLING: 92% SIMD-idle (s_sleep + s_barrier parking) invites DPM to
// drop core clocks, inflating every latency term in wall time. Fix attempt:
// the polling wave BUSY-SPINS with a dependent FMA chain between sweeps (no
// s_sleep) to keep the CU active and clocks pinned. Side benefit: VALUBusy
// becomes a direct readout of the spin fraction (instrumentation via PMC).
__device__ __forceinline__ void bar_arrive(unsigned* slot, int bid, unsigned barno) {
    __syncthreads();   // s_waitcnt vmcnt(0): all sc1 h-stores acked at LLC
    if (threadIdx.x == 0)
        __hip_atomic_store(&slot[bid * 64], barno + 1u, __ATOMIC_RELAXED,
                           __HIP_MEMORY_SCOPE_AGENT);
    // NO trailing sync: other waves fall through into h-independent work.
}
__device__ __forceinline__ void bar_wait(unsigned* slot, int mg, unsigned barno) {
    if (threadIdx.x < 64) {
        const unsigned tgt = barno + 1u;
        unsigned* p0 = &slot[(mg * 128 + threadIdx.x) * 64];
        unsigned* p1 = p0 + 64 * 64;
        unsigned spins = 0;
        float keep = (float)barno;   // VALU keep-alive chain (anti-throttle)
        for (;;) {
            unsigned v0 = __hip_atomic_load(p0, __ATOMIC_RELAXED,
                                            __HIP_MEMORY_SCOPE_AGENT);
            unsigned v1 = __hip_atomic_load(p1, __ATOMIC_RELAXED,
                                            __HIP_MEMORY_SCOPE_AGENT);
            if (__all(v0 >= tgt && v1 >= tgt)) break;
#pragma unroll
            for (int i = 0; i < 32; ++i)          // ~32 dependent VALU cycles
                keep = __builtin_fmaf(keep, 1.0000001f, 1.0f);
            if (++spins > (1u << 22)) break;   // safety valve: corrupt-but-return
        }
        asm volatile("" :: "v"(keep));   // keep the chain live (no DCE)
    }
    __syncthreads();   // drains the overlapped nt out-stores + x loads
}

// ---------- prep: zero slots + h buffer 0, fp32 x -> fp16 ----------
__global__ void prep_kernel(const float* __restrict__ x, _Float16* __restrict__ xbuf,
                            unsigned* __restrict__ ctr, unsigned* __restrict__ hb0u) {
    const int gtid = blockIdx.x * blockDim.x + threadIdx.x;
    if (gtid < 16384) ctr[gtid] = 0u;         // 256 slots x 256-B stride = 64 KB
    if (gtid < 65536) hb0u[gtid] = 0u;        // h(0): 128x1024 fp16 = 256 KB
    const f4* src = (const f4*)x;
    h4* dst = (h4*)xbuf;
    const int stride = gridDim.x * blockDim.x;    // 524288
    for (int i = gtid; i < 8388608; i += stride)  // T*B*D/4
        dst[i] = __builtin_convertvector(src[i], h4);
}

// ---------- persistent LSTM ----------
// 256 blocks x 256 threads. Block b: mg = b>>7 (rows mg*64..+63), ug = b&127,
// units u0 = ug*8 .. +7, all 4 gates -> 32 preact cols (2 MFMA n-tiles).
// ALL of W (K=2048) in LDS, conflict-free chunk layout (see staging below).
// Loop structure per step t:
//   [a-regs already hold the x-half partial sums for step t]
//   bar_wait(t-1)            <- all 128 mg slots reached t (busy-poll sweep)
//   h-half MFMAs (kc 32..63) <- ROT: plain cached h8 loads (fresh addresses)
//   epilogue: activations, c/h update, h(t+1) via packed sc1 atomic stores
//   bar_arrive(t)            <- vmcnt(0) drain, own-slot store (1 LLC hop)
//   nt out stores for step t <- no L2 allocate (R12 showed normal stores add
//                               ~28MB RFO FETCH + ~0.5us/step regression)
//   x-half MFMAs for t+1     <- executes INSIDE the barrier window
#define XHALF                                                                  \
    _Pragma("unroll")                                                          \
    for (int kc = 0; kc < 32; kc += 2) {                                       \
        h8 av0 = *(const h8*)(xA + kc * 32);                                   \
        h8 av1 = *(const h8*)(xA + kc * 32 + 32);                              \
        h8 b00 = *(const h8*)&wsm[kc * 1024 + boff];                           \
        h8 b10 = *(const h8*)&wsm[kc * 1024 + boff + 512];                     \
        h8 b01 = *(const h8*)&wsm[(kc + 1) * 1024 + boff];                     \
        h8 b11 = *(const h8*)&wsm[(kc + 1) * 1024 + boff + 512];               \
        a00 = __builtin_amdgcn_mfma_f32_16x16x32_f16(av0, b00, a00, 0, 0, 0);  \
        a10 = __builtin_amdgcn_mfma_f32_16x16x32_f16(av0, b10, a10, 0, 0, 0);  \
        a01 = __builtin_amdgcn_mfma_f32_16x16x32_f16(av1, b01, a01, 0, 0, 0);  \
        a11 = __builtin_amdgcn_mfma_f32_16x16x32_f16(av1, b11, a11, 0, 0, 0);  \
    }

// sc1 (LLC-coherent) h8 load: two agent-relaxed u64 atomic loads (PP fallback).
#define LDH8(dst, elemoff)                                                     \
    do {                                                                       \
        union { u64 q[2]; h8 v; } u_;                                          \
        u64* p_ = (u64*)(hA + (elemoff));                                      \
        u_.q[0] = __hip_atomic_load(p_,     __ATOMIC_RELAXED,                  \
                                    __HIP_MEMORY_SCOPE_AGENT);                 \
        u_.q[1] = __hip_atomic_load(p_ + 1, __ATOMIC_RELAXED,                  \
                                    __HIP_MEMORY_SCOPE_AGENT);                 \
        dst = u_.v;                                                            \
    } while (0)

template<bool ROT>
__global__ __launch_bounds__(256, 1)
void lstm_kernel(const _Float16* __restrict__ xbuf,
                 _Float16* __restrict__ hb0, _Float16* __restrict__ hb1,
                 const float* __restrict__ Wf, const float* __restrict__ bfp,
                 const float* __restrict__ Wi, const float* __restrict__ bip,
                 const float* __restrict__ Wg, const float* __restrict__ bgp,
                 const float* __restrict__ Wo, const float* __restrict__ bop,
                 float* __restrict__ out,
                 unsigned* __restrict__ slot) {
    __shared__ _Float16 wsm[64 * 1024];   // 128 KB: full W slice, chunked

    const int tid = threadIdx.x;
    const int bid = blockIdx.x;
    const int mg = bid >> 7;
    const int ug = bid & 127;
    const int u0 = ug << 3;

    const float* WSEL[4] = {Wf, Wi, Wg, Wo};

    // ---- stage W slice (32 cols x 2048 k) fp32 -> fp16 LDS, chunked ----
    // f16 idx = kc*1024 + tile*512 + quad*128 + row16*8 + j
    // (kc = k>>5, quad = (k>>3)&3, j = k&7, col = tile*16 + row16)
    // Read addr for lane L (= quad*16+row16): byte = kc*2048 + tile*1024 + L*16
    //   -> perfectly contiguous 16 B/lane -> zero bank conflicts.
    {
        const int col = tid & 31;                  // preact col
        const int kseg = tid >> 5;                 // 0..7, 256 k each
        const float* srcp = WSEL[col >> 3] + (size_t)(u0 + (col & 7)) * 2048
                          + kseg * 256;
        const int cbase = (col >> 4) * 512 + (col & 15) * 8;
#pragma unroll 8
        for (int k4 = 0; k4 < 256; k4 += 4) {
            const int k = kseg * 256 + k4;
            f4 v = *(const f4*)(srcp + k4);
            h4 hv = __builtin_convertvector(v, h4);
            *(h4*)&wsm[(k >> 5) * 1024 + cbase + ((k >> 3) & 3) * 128 + (k & 7)] = hv;
        }
    }

    // ---- per-lane constants ----
    const int lane  = tid & 63;
    const int wv    = tid >> 6;        // wave -> m-strip
    const int row16 = lane & 15;
    const int quad  = lane >> 4;
    const int uu    = lane & 7;

    __syncthreads();   // W staged (block-local)

    const float bias_f = bfp[u0 + uu];
    const float bias_i = bip[u0 + uu];
    const float bias_g = bgp[u0 + uu];
    const float bias_o = bop[u0 + uu];

    const int zrow = mg * 64 + wv * 16 + row16;
    const int boff = quad * 128 + row16 * 8;      // lane*8 f16 = lane*16 B
    const int drow = mg * 64 + wv * 16 + quad * 4;
    const bool writer = (lane & 8) == 0;
    const bool pstore = writer && ((uu & 1) == 0);   // even-unit writer: packs pair
    const bool himask = (lane & 8) != 0;

    const _Float16* hbv[2] = {hb0, hb1};
    const size_t aoff = (size_t)zrow * 1024 + quad * 8;
    const _Float16* xbase = xbuf + aoff;
    const size_t obase = (size_t)drow * 1024 + u0 + uu;   // row j adds j*1024

    float cc[4] = {0.f, 0.f, 0.f, 0.f};
    float hnv[4];                                  // step-t h values, stored late

    // ---- prologue: x-half for t = 0 (h(0)=0 already staged by prep) ----
    f4 a00 = {0.f,0.f,0.f,0.f}, a01 = {0.f,0.f,0.f,0.f};
    f4 a10 = {0.f,0.f,0.f,0.f}, a11 = {0.f,0.f,0.f,0.f};
    {
        const _Float16* xA = xbase;
        XHALF
    }

    for (int t = 0; t < 256; ++t) {
        if (t) bar_wait(slot, mg, (unsigned)(t - 1));   // h(t) released

        const _Float16* hA = (ROT ? hb0 + (size_t)t * 131072 : hbv[t & 1]) + aoff;
        unsigned* hwu = (unsigned*)(ROT ? hb0 + (size_t)(t + 1) * 131072
                                        : hbv[(t + 1) & 1]);

        // h half: k chunks 32..63 (the only h-dependent work)
#pragma unroll
        for (int kc = 32; kc < 64; kc += 2) {
            h8 av0, av1;
            if constexpr (ROT) {
                // plain cached loads: address is write-once/read-once, so no
                // stale L1/L2 line can exist; miss path reads fresh LLC data
                av0 = *(const h8*)(hA + (kc - 32) * 32);
                av1 = *(const h8*)(hA + (kc - 32) * 32 + 32);
            } else {
                LDH8(av0, (kc - 32) * 32);
                LDH8(av1, (kc - 32) * 32 + 32);
            }
            h8 b00 = *(const h8*)&wsm[kc * 1024 + boff];
            h8 b10 = *(const h8*)&wsm[kc * 1024 + boff + 512];
            h8 b01 = *(const h8*)&wsm[(kc + 1) * 1024 + boff];
            h8 b11 = *(const h8*)&wsm[(kc + 1) * 1024 + boff + 512];
            a00 = __builtin_amdgcn_mfma_f32_16x16x32_f16(av0, b00, a00, 0, 0, 0);
            a10 = __builtin_amdgcn_mfma_f32_16x16x32_f16(av0, b10, a10, 0, 0, 0);
            a01 = __builtin_amdgcn_mfma_f32_16x16x32_f16(av1, b01, a01, 0, 0, 0);
            a11 = __builtin_amdgcn_mfma_f32_16x16x32_f16(av1, b11, a11, 0, 0, 0);
        }

        // ---- epilogue: gather gate pairs, activations, state update ----
        f4 s0 = a00 + a01;   // tile0: f|i preacts, col = lane&15
        f4 s1 = a10 + a11;   // tile1: g|o preacts
        float q0[4], q1[4];
#pragma unroll
        for (int j = 0; j < 4; ++j) {
            q0[j] = __shfl_xor(s0[j], 8, 64);
            q1[j] = __shfl_xor(s1[j], 8, 64);
        }
#pragma unroll
        for (int j = 0; j < 4; ++j) {
            float pf = himask ? q0[j] : s0[j];
            float pi = himask ? s0[j] : q0[j];
            float pg = himask ? q1[j] : s1[j];
            float po = himask ? s1[j] : q1[j];
            float fg = sigm(pf + bias_f);
            float ig = sigm(pi + bias_i);
            float gg = tanh_fast(pg + bias_g);
            float og = sigm(po + bias_o);
            float cn = fg * cc[j] + ig * gg;
            cc[j] = cn;
            float hn = og * tanh_fast(cn);
            hnv[j] = hn;
            // h(t+1) feedback: packed 2xfp16 agent-atomic store (sc1 ->
            // write-through to LLC; no dirty L2 line, no fence needed).
            float hp = __shfl_xor(hn, 1, 64);     // odd neighbor's value
            if (pstore) {
                _Float16 alo = (_Float16)hn, ahi = (_Float16)hp;
                unsigned short blo, bhi;
                __builtin_memcpy(&blo, &alo, 2);
                __builtin_memcpy(&bhi, &ahi, 2);
                unsigned pk = (unsigned)blo | ((unsigned)bhi << 16);
                __hip_atomic_store(&hwu[(obase >> 1) + (size_t)j * 512], pk,
                                   __ATOMIC_RELAXED, __HIP_MEMORY_SCOPE_AGENT);
            }
        }

        if (t < 255) {
            bar_arrive(slot, bid, (unsigned)t);  // vmcnt(0) drain + own-slot store
            // deferred nt out stores for step t: fire-and-forget, acks drain
            // at the NEXT bar_wait's __syncthreads, overlapped w/ sweep+XHALF
            if (writer) {
                float* outb = out + (size_t)t * 131072;
#pragma unroll
                for (int j = 0; j < 4; ++j)
                    __builtin_nontemporal_store(hnv[j], &outb[obase + (size_t)j * 1024]);
            }
            // x-half for t+1: h-independent, runs inside the barrier window
            a00 = (f4){0.f,0.f,0.f,0.f}; a01 = (f4){0.f,0.f,0.f,0.f};
            a10 = (f4){0.f,0.f,0.f,0.f}; a11 = (f4){0.f,0.f,0.f,0.f};
            const _Float16* xA = xbase + (size_t)(t + 1) * 131072;
            XHALF
        } else if (writer) {
            // t = 255: no barrier follows; store outputs[255] + hx directly
            float* outb = out + (size_t)255 * 131072;
#pragma unroll
            for (int j = 0; j < 4; ++j) {
                __builtin_nontemporal_store(hnv[j], &outb[obase + (size_t)j * 1024]);
                __builtin_nontemporal_store(hnv[j], &out[33554432 + obase + (size_t)j * 1024]);
            }
        }
    }
    // cx
    if (writer) {
#pragma unroll
        for (int j = 0; j < 4; ++j)
            __builtin_nontemporal_store(
                cc[j], &out[33554432 + 131072 + obase + (size_t)j * 1024]);
    }
}

extern "C" void kernel_launch(void* const* d_in, const int* in_sizes, int n_in,
                              void* d_out, int out_size, void* d_ws, size_t ws_size,
                              hipStream_t stream) {
    const float* x  = (const float*)d_in[0];
    const float* Wf = (const float*)d_in[1];
    const float* bf = (const float*)d_in[2];
    const float* Wi = (const float*)d_in[3];
    const float* bi = (const float*)d_in[4];
    const float* Wg = (const float*)d_in[5];
    const float* bg = (const float*)d_in[6];
    const float* Wo = (const float*)d_in[7];
    const float* bo = (const float*)d_in[8];
    float* out = (float*)d_out;

    unsigned char* ws = (unsigned char*)d_ws;
    unsigned* slot = (unsigned*)ws;                       // 256 slots, 256-B stride
    _Float16* hbase = (_Float16*)(ws + 65536);            // rot: 257 bufs / pp: hb0

    // Rotating layout: slots 64 KB | h buffers 257 x 256 KB | xbuf 64 MB
    const size_t HROT = 257ull * 262144ull;               // 67,371,008 B
    const size_t ROT_NEED = 65536ull + HROT + 67108864ull;
    const bool rot = (ws_size >= ROT_NEED);

    _Float16* hb1  = (_Float16*)(ws + 65536 + 262144);    // pp fallback only
    _Float16* xbuf = rot ? (_Float16*)(ws + 65536 + HROT)
                         : (_Float16*)(ws + 65536 + 524288);

    prep_kernel<<<2048, 256, 0, stream>>>(x, xbuf, slot, (unsigned*)hbase);
    if (rot)
        lstm_kernel<true><<<NBLK, 256, 0, stream>>>(xbuf, hbase, hb1,
                                                    Wf, bf, Wi, bi, Wg, bg, Wo, bo,
                                                    out, slot);
    else
        lstm_kernel<false><<<NBLK, 256, 0, stream>>>(xbuf, hbase, hb1,
                                                     Wf, bf, Wi, bi, Wg, bg, Wo, bo,
                                                     out, slot);
}

// Round 19
// 2654.581 us; speedup vs baseline: 1.2635x; 1.2126x over previous
//
#include <hip/hip_runtime.h>

// ---------- types ----------
typedef _Float16 h8 __attribute__((ext_vector_type(8)));
typedef _Float16 h4 __attribute__((ext_vector_type(4)));
typedef float    f4 __attribute__((ext_vector_type(4)));
typedef unsigned long long u64;

#define NBLK 256   // persistent grid = 256 blocks = 1 per CU

__device__ __forceinline__ float sigm(float x) {
    return 1.0f / (1.0f + __expf(-x));
}
__device__ __forceinline__ float tanh_fast(float x) {
    return 1.0f - 2.0f / (__expf(2.0f * x) + 1.0f);   // saturates correctly at +/-inf
}

// ---------- prep: zero slots + h buffer 0, fp32 x -> fp16 ----------
__global__ void prep_kernel(const float* __restrict__ x, _Float16* __restrict__ xbuf,
                            unsigned* __restrict__ ctr, unsigned* __restrict__ hb0u) {
    const int gtid = blockIdx.x * blockDim.x + threadIdx.x;
    if (gtid < 16384) ctr[gtid] = 0u;         // 256 slots x 256-B stride = 64 KB
    if (gtid < 65536) hb0u[gtid] = 0u;        // h(0): 128x1024 fp16 = 256 KB
    const f4* src = (const f4*)x;
    h4* dst = (h4*)xbuf;
    const int stride = gridDim.x * blockDim.x;    // 524288
    for (int i = gtid; i < 8388608; i += stride)  // T*B*D/4
        dst[i] = __builtin_convertvector(src[i], h4);
}

// ---------- persistent LSTM, 8-WAVE ROLE-SPLIT ----------
// R18 post-mortem: busy-poll neutral (throttle refuted); VALUBusy delta shows
// spin ~3% of time -> the ~12us/step floor is PER-BLOCK SERIAL MEMORY LATENCY:
// two sequential latency-bound load phases (h-half 32 loads, x-half 32 loads,
// fresh addresses, ~8 in flight/wave at 4 waves/CU). Fix: 512 threads.
//   waves 0-3 (h-waves): grid-wait, h-half GEMM, epilogue, sc1 h-stores, out.
//   waves 4-7 (x-waves): x-half GEMM for t+1 CONCURRENTLY; partial sums handed
//                        to h-waves via 8 KB LDS buffer (xp).
// -> 2 waves/SIMD issuing loads (2x MLP) and the x-load phase leaves the
// serial path entirely. Barrier protocol (flat slots, sc1, fence-free),
// rotating-h, MFMA tiling, epilogue math: unchanged from the verified lineage.
// Sync schedule per step t:
//   [wave0 polls slots >= t] -> S1 (__syncthreads: h(t) ready, xp(t) in LDS)
//   h-waves: h-half(t); s = hacc + xp(t); epilogue; sc1 h(t+1) stores
//   x-waves: x-half(t+1) into regs
//   S2 (__syncthreads: xp(t) consumed by h-waves; h sc1 stores vmcnt-drained)
//   x-waves: write xp(t+1) | tid0: slot=t+1 (release) | h-writers: nt out(t)
// Hazards: xp write(t+1) after S2(t), read after S1(t+1) -> ordered. Slot
// store after S2 whose per-wave vmcnt(0) acks all h sc1 stores -> release ok.
#define XHALF                                                                  \
    _Pragma("unroll")                                                          \
    for (int kc = 0; kc < 32; kc += 2) {                                       \
        h8 av0 = *(const h8*)(xA + kc * 32);                                   \
        h8 av1 = *(const h8*)(xA + kc * 32 + 32);                              \
        h8 b00 = *(const h8*)&wsm[kc * 1024 + boff];                           \
        h8 b10 = *(const h8*)&wsm[kc * 1024 + boff + 512];                     \
        h8 b01 = *(const h8*)&wsm[(kc + 1) * 1024 + boff];                     \
        h8 b11 = *(const h8*)&wsm[(kc + 1) * 1024 + boff + 512];               \
        a00 = __builtin_amdgcn_mfma_f32_16x16x32_f16(av0, b00, a00, 0, 0, 0);  \
        a10 = __builtin_amdgcn_mfma_f32_16x16x32_f16(av0, b10, a10, 0, 0, 0);  \
        a01 = __builtin_amdgcn_mfma_f32_16x16x32_f16(av1, b01, a01, 0, 0, 0);  \
        a11 = __builtin_amdgcn_mfma_f32_16x16x32_f16(av1, b11, a11, 0, 0, 0);  \
    }

// sc1 (LLC-coherent) h8 load: two agent-relaxed u64 atomic loads (PP fallback).
#define LDH8(dst, elemoff)                                                     \
    do {                                                                       \
        union { u64 q[2]; h8 v; } u_;                                          \
        u64* p_ = (u64*)(hA + (elemoff));                                      \
        u_.q[0] = __hip_atomic_load(p_,     __ATOMIC_RELAXED,                  \
                                    __HIP_MEMORY_SCOPE_AGENT);                 \
        u_.q[1] = __hip_atomic_load(p_ + 1, __ATOMIC_RELAXED,                  \
                                    __HIP_MEMORY_SCOPE_AGENT);                 \
        dst = u_.v;                                                            \
    } while (0)

template<bool ROT>
__global__ __launch_bounds__(512, 1)
void lstm_kernel(const _Float16* __restrict__ xbuf,
                 _Float16* __restrict__ hb0, _Float16* __restrict__ hb1,
                 const float* __restrict__ Wf, const float* __restrict__ bfp,
                 const float* __restrict__ Wi, const float* __restrict__ bip,
                 const float* __restrict__ Wg, const float* __restrict__ bgp,
                 const float* __restrict__ Wo, const float* __restrict__ bop,
                 float* __restrict__ out,
                 unsigned* __restrict__ slot) {
    __shared__ _Float16 wsm[64 * 1024];   // 128 KB: full W slice, chunked
    __shared__ float xp[4 * 64 * 8];      // 8 KB: x-partial handoff (per strip/lane)

    const int tid = threadIdx.x;
    const int bid = blockIdx.x;
    const int mg = bid >> 7;
    const int ug = bid & 127;
    const int u0 = ug << 3;
    const int wv8 = tid >> 6;             // 0..7
    const bool hwave = wv8 < 4;
    const int strip = wv8 & 3;            // m-strip (16 rows) for both roles

    const float* WSEL[4] = {Wf, Wi, Wg, Wo};

    // ---- stage W slice (32 cols x 2048 k) fp32 -> fp16 LDS, chunked ----
    // 512 threads: col = tid&31, kseg = tid>>5 (0..15, 128 k each).
    // Layout/read addressing unchanged: conflict-free 16 B/lane reads.
    {
        const int col = tid & 31;                  // preact col
        const int kseg = tid >> 5;                 // 0..15, 128 k each
        const float* srcp = WSEL[col >> 3] + (size_t)(u0 + (col & 7)) * 2048
                          + kseg * 128;
        const int cbase = (col >> 4) * 512 + (col & 15) * 8;
#pragma unroll 8
        for (int k4 = 0; k4 < 128; k4 += 4) {
            const int k = kseg * 128 + k4;
            f4 v = *(const f4*)(srcp + k4);
            h4 hv = __builtin_convertvector(v, h4);
            *(h4*)&wsm[(k >> 5) * 1024 + cbase + ((k >> 3) & 3) * 128 + (k & 7)] = hv;
        }
    }

    // ---- per-lane constants ----
    const int lane  = tid & 63;
    const int row16 = lane & 15;
    const int quad  = lane >> 4;
    const int uu    = lane & 7;

    __syncthreads();   // W staged (block-local)

    const float bias_f = bfp[u0 + uu];
    const float bias_i = bip[u0 + uu];
    const float bias_g = bgp[u0 + uu];
    const float bias_o = bop[u0 + uu];

    const int zrow = mg * 64 + strip * 16 + row16;
    const int boff = quad * 128 + row16 * 8;      // lane*8 f16 = lane*16 B
    const int drow = mg * 64 + strip * 16 + quad * 4;
    const bool writer = (lane & 8) == 0;
    const bool pstore = writer && ((uu & 1) == 0);   // even-unit writer: packs pair
    const bool himask = (lane & 8) != 0;

    const _Float16* hbv[2] = {hb0, hb1};
    const size_t aoff = (size_t)zrow * 1024 + quad * 8;
    const _Float16* xbase = xbuf + aoff;
    const size_t obase = (size_t)drow * 1024 + u0 + uu;   // row j adds j*1024
    const int xpb = (strip * 64 + lane) * 8;

    float cc[4] = {0.f, 0.f, 0.f, 0.f};
    float hnv[4];                                  // step-t h values (h-waves)

    f4 a00 = {0.f,0.f,0.f,0.f}, a01 = {0.f,0.f,0.f,0.f};
    f4 a10 = {0.f,0.f,0.f,0.f}, a11 = {0.f,0.f,0.f,0.f};

    // ---- prologue: x-waves compute x-half(0) and publish partials ----
    if (!hwave) {
        const _Float16* xA = xbase;
        XHALF
        *(f4*)&xp[xpb]     = a00 + a01;
        *(f4*)&xp[xpb + 4] = a10 + a11;
    }

    for (int t = 0; t < 256; ++t) {
        // ---- grid wait: all 128 mg slots >= t (wave 0 sweeps) ----
        if (t && tid < 64) {
            const unsigned tgt = (unsigned)t;
            unsigned* p0 = &slot[(mg * 128 + lane) * 64];
            unsigned* p1 = p0 + 64 * 64;
            unsigned spins = 0;
            for (;;) {
                unsigned v0 = __hip_atomic_load(p0, __ATOMIC_RELAXED,
                                                __HIP_MEMORY_SCOPE_AGENT);
                unsigned v1 = __hip_atomic_load(p1, __ATOMIC_RELAXED,
                                                __HIP_MEMORY_SCOPE_AGENT);
                if (__all(v0 >= tgt && v1 >= tgt)) break;
                __builtin_amdgcn_s_sleep(2);
                if (++spins > (1u << 24)) break;   // safety valve
            }
        }
        __syncthreads();   // S1: h(t) ready grid-wide; xp(t) visible in LDS

        if (hwave) {
            const _Float16* hA = (ROT ? hb0 + (size_t)t * 131072 : hbv[t & 1]) + aoff;
            unsigned* hwu = (unsigned*)(ROT ? hb0 + (size_t)(t + 1) * 131072
                                            : hbv[(t + 1) & 1]);
            a00 = (f4){0.f,0.f,0.f,0.f}; a01 = (f4){0.f,0.f,0.f,0.f};
            a10 = (f4){0.f,0.f,0.f,0.f}; a11 = (f4){0.f,0.f,0.f,0.f};
            // h half: k chunks 32..63 (the only h-dependent GEMM work)
#pragma unroll
            for (int kc = 32; kc < 64; kc += 2) {
                h8 av0, av1;
                if constexpr (ROT) {
                    // plain cached loads: write-once/read-once addresses ->
                    // no stale-line hazard; miss path reads fresh LLC data
                    av0 = *(const h8*)(hA + (kc - 32) * 32);
                    av1 = *(const h8*)(hA + (kc - 32) * 32 + 32);
                } else {
                    LDH8(av0, (kc - 32) * 32);
                    LDH8(av1, (kc - 32) * 32 + 32);
                }
                h8 b00 = *(const h8*)&wsm[kc * 1024 + boff];
                h8 b10 = *(const h8*)&wsm[kc * 1024 + boff + 512];
                h8 b01 = *(const h8*)&wsm[(kc + 1) * 1024 + boff];
                h8 b11 = *(const h8*)&wsm[(kc + 1) * 1024 + boff + 512];
                a00 = __builtin_amdgcn_mfma_f32_16x16x32_f16(av0, b00, a00, 0, 0, 0);
                a10 = __builtin_amdgcn_mfma_f32_16x16x32_f16(av0, b10, a10, 0, 0, 0);
                a01 = __builtin_amdgcn_mfma_f32_16x16x32_f16(av1, b01, a01, 0, 0, 0);
                a11 = __builtin_amdgcn_mfma_f32_16x16x32_f16(av1, b11, a11, 0, 0, 0);
            }

            // ---- epilogue: h-partials + x-partials (LDS), activations ----
            f4 s0 = a00 + a01 + *(const f4*)&xp[xpb];       // f|i preacts
            f4 s1 = a10 + a11 + *(const f4*)&xp[xpb + 4];   // g|o preacts
            float q0[4], q1[4];
#pragma unroll
            for (int j = 0; j < 4; ++j) {
                q0[j] = __shfl_xor(s0[j], 8, 64);
                q1[j] = __shfl_xor(s1[j], 8, 64);
            }
#pragma unroll
            for (int j = 0; j < 4; ++j) {
                float pf = himask ? q0[j] : s0[j];
                float pi = himask ? s0[j] : q0[j];
                float pg = himask ? q1[j] : s1[j];
                float po = himask ? s1[j] : q1[j];
                float fg = sigm(pf + bias_f);
                float ig = sigm(pi + bias_i);
                float gg = tanh_fast(pg + bias_g);
                float og = sigm(po + bias_o);
                float cn = fg * cc[j] + ig * gg;
                cc[j] = cn;
                float hn = og * tanh_fast(cn);
                hnv[j] = hn;
                // h(t+1): packed 2xfp16 agent-atomic store (sc1 -> LLC)
                float hp = __shfl_xor(hn, 1, 64);     // odd neighbor's value
                if (pstore) {
                    _Float16 alo = (_Float16)hn, ahi = (_Float16)hp;
                    unsigned short blo, bhi;
                    __builtin_memcpy(&blo, &alo, 2);
                    __builtin_memcpy(&bhi, &ahi, 2);
                    unsigned pk = (unsigned)blo | ((unsigned)bhi << 16);
                    __hip_atomic_store(&hwu[(obase >> 1) + (size_t)j * 512], pk,
                                       __ATOMIC_RELAXED, __HIP_MEMORY_SCOPE_AGENT);
                }
            }
        } else if (t < 255) {
            // x-waves: x-half for step t+1, concurrent with h-waves' work
            a00 = (f4){0.f,0.f,0.f,0.f}; a01 = (f4){0.f,0.f,0.f,0.f};
            a10 = (f4){0.f,0.f,0.f,0.f}; a11 = (f4){0.f,0.f,0.f,0.f};
            const _Float16* xA = xbase + (size_t)(t + 1) * 131072;
            XHALF
        }

        __syncthreads();   // S2: xp(t) consumed; all h sc1 stores vmcnt-drained

        if (!hwave && t < 255) {
            *(f4*)&xp[xpb]     = a00 + a01;   // publish x-partials(t+1)
            *(f4*)&xp[xpb + 4] = a10 + a11;
        }
        if (t < 255) {
            if (tid == 0)   // release h(t+1): own-slot store (1 LLC hop)
                __hip_atomic_store(&slot[bid * 64], (unsigned)(t + 1),
                                   __ATOMIC_RELAXED, __HIP_MEMORY_SCOPE_AGENT);
            if (hwave && writer) {
                // nt out stores: fire-and-forget, drain overlapped at next S1
                float* outb = out + (size_t)t * 131072;
#pragma unroll
                for (int j = 0; j < 4; ++j)
                    __builtin_nontemporal_store(hnv[j], &outb[obase + (size_t)j * 1024]);
            }
        } else if (hwave && writer) {
            // t = 255: outputs[255] + hx
            float* outb = out + (size_t)255 * 131072;
#pragma unroll
            for (int j = 0; j < 4; ++j) {
                __builtin_nontemporal_store(hnv[j], &outb[obase + (size_t)j * 1024]);
                __builtin_nontemporal_store(hnv[j], &out[33554432 + obase + (size_t)j * 1024]);
            }
        }
    }
    // cx
    if (hwave && writer) {
#pragma unroll
        for (int j = 0; j < 4; ++j)
            __builtin_nontemporal_store(
                cc[j], &out[33554432 + 131072 + obase + (size_t)j * 1024]);
    }
}

extern "C" void kernel_launch(void* const* d_in, const int* in_sizes, int n_in,
                              void* d_out, int out_size, void* d_ws, size_t ws_size,
                              hipStream_t stream) {
    const float* x  = (const float*)d_in[0];
    const float* Wf = (const float*)d_in[1];
    const float* bf = (const float*)d_in[2];
    const float* Wi = (const float*)d_in[3];
    const float* bi = (const float*)d_in[4];
    const float* Wg = (const float*)d_in[5];
    const float* bg = (const float*)d_in[6];
    const float* Wo = (const float*)d_in[7];
    const float* bo = (const float*)d_in[8];
    float* out = (float*)d_out;

    unsigned char* ws = (unsigned char*)d_ws;
    unsigned* slot = (unsigned*)ws;                       // 256 slots, 256-B stride
    _Float16* hbase = (_Float16*)(ws + 65536);            // rot: 257 bufs / pp: hb0

    // Rotating layout: slots 64 KB | h buffers 257 x 256 KB | xbuf 64 MB
    const size_t HROT = 257ull * 262144ull;               // 67,371,008 B
    const size_t ROT_NEED = 65536ull + HROT + 67108864ull;
    const bool rot = (ws_size >= ROT_NEED);

    _Float16* hb1  = (_Float16*)(ws + 65536 + 262144);    // pp fallback only
    _Float16* xbuf = rot ? (_Float16*)(ws + 65536 + HROT)
                         : (_Float16*)(ws + 65536 + 524288);

    prep_kernel<<<2048, 256, 0, stream>>>(x, xbuf, slot, (unsigned*)hbase);
    if (rot)
        lstm_kernel<true><<<NBLK, 512, 0, stream>>>(xbuf, hbase, hb1,
                                                    Wf, bf, Wi, bi, Wg, bg, Wo, bo,
                                                    out, slot);
    else
        lstm_kernel<false><<<NBLK, 512, 0, stream>>>(xbuf, hbase, hb1,
                                                     Wf, bf, Wi, bi, Wg, bg, Wo, bo,
                                                     out, slot);
}